// Round 12
// baseline (217.173 us; speedup 1.0000x reference)
//
#include <hip/hip_runtime.h>
#include <hip/hip_bf16.h>

#define B_     4
#define V_IN   12500
#define V_OUT  50000
#define C_IN   64
#define C_OUT  32
#define SPIRAL 9
#define K_NNZ  3
#define ROWS   (B_ * V_OUT)       // 200000
#define KDIM   (SPIRAL * C_IN)    // 576
#define KSTEPS (KDIM / 32)        // 18 (16x16x32 MFMA)
#define WFRAG_ELEMS (KSTEPS * 2 * 64 * 8)  // 18432 bf16 = 36864 B
#define HALF_V (V_OUT / 2)        // 25000: working-set split point

#define GROUPS_PER_B (V_OUT / 16) // 3125 16-row groups per batch (k1)
#define G1           2048         // k1 blocks (+1 W-prep); 256 per XCD
#define TILES_PER_B  782          // 781 full 64-row tiles + one 16-row tail (k2)
#define G2           1024         // k2 blocks; 4 blocks/CU (16 waves/CU), LDS-bound
#define MAXT         4            // max tiles per wave-slot (782/256 -> 3 or 4)

typedef __attribute__((ext_vector_type(8))) short short8_t;   // 8 bf16 (4 VGPRs)
typedef __attribute__((ext_vector_type(4))) float floatx4;    // 4 fp32 acc

__device__ __forceinline__ unsigned short f32_to_bf16(float f) {
    unsigned int u = __float_as_uint(f);
    unsigned int r = u + 0x7fffu + ((u >> 16) & 1u);   // round-to-nearest-even
    return (unsigned short)(r >> 16);
}

// ---------------- Kernel 1: upsample, 2-wide ILP (unchanged from R9) --------
__global__ __launch_bounds__(256) void upsample_kernel(
    const float* __restrict__ x,
    const int* __restrict__ up_idx,
    const float* __restrict__ up_val,
    const float* __restrict__ weight,
    unsigned short* __restrict__ up_bf16,
    unsigned short* __restrict__ w_frag)
{
    int tid = threadIdx.x;
    if (blockIdx.x == G1) {
        for (int idx = tid; idx < WFRAG_ELEMS; idx += 256) {
            int j     = idx & 7;
            int lane  = (idx >> 3) & 63;
            int ntile = (idx >> 9) & 1;
            int kstep = idx >> 10;
            int k = kstep * 32 + (lane >> 4) * 8 + j;
            int n = ntile * 16 + (lane & 15);
            w_frag[idx] = f32_to_bf16(weight[k * C_OUT + n]);
        }
        return;
    }
    int xcd  = blockIdx.x & 7;
    int b    = xcd >> 1;                    // batch owned by this XCD pair
    int h    = xcd & 1;
    int j    = blockIdx.x >> 3;             // [0, 256)
    int slot = h + 2 * j;                   // [0, 512)
    int lane16 = tid & 15;                  // 4 channels each
    int sub    = tid >> 4;                  // row within 16-row group

    const float* xb = x + (size_t)b * V_IN * C_IN;
    unsigned short* upb = up_bf16 + (size_t)b * V_OUT * C_IN;

    for (int gl = slot; gl < GROUPS_PER_B; gl += 1024) {
        int gl2  = gl + 512;
        int has2 = gl2 < GROUPS_PER_B;
        int v1 = gl * 16 + sub;
        int v2 = has2 ? gl2 * 16 + sub : v1;
        int   u10 = up_idx[v1 * K_NNZ + 0], u11 = up_idx[v1 * K_NNZ + 1], u12 = up_idx[v1 * K_NNZ + 2];
        int   u20 = up_idx[v2 * K_NNZ + 0], u21 = up_idx[v2 * K_NNZ + 1], u22 = up_idx[v2 * K_NNZ + 2];
        float c10 = up_val[v1 * K_NNZ + 0], c11 = up_val[v1 * K_NNZ + 1], c12 = up_val[v1 * K_NNZ + 2];
        float c20 = up_val[v2 * K_NNZ + 0], c21 = up_val[v2 * K_NNZ + 1], c22 = up_val[v2 * K_NNZ + 2];
        float4 xa0 = *((const float4*)(xb + (size_t)u10 * C_IN) + lane16);
        float4 xa1 = *((const float4*)(xb + (size_t)u11 * C_IN) + lane16);
        float4 xa2 = *((const float4*)(xb + (size_t)u12 * C_IN) + lane16);
        float4 xb0 = *((const float4*)(xb + (size_t)u20 * C_IN) + lane16);
        float4 xb1 = *((const float4*)(xb + (size_t)u21 * C_IN) + lane16);
        float4 xb2 = *((const float4*)(xb + (size_t)u22 * C_IN) + lane16);
        ushort4 o1, o2;
        o1.x = f32_to_bf16(c10 * xa0.x + c11 * xa1.x + c12 * xa2.x);
        o1.y = f32_to_bf16(c10 * xa0.y + c11 * xa1.y + c12 * xa2.y);
        o1.z = f32_to_bf16(c10 * xa0.z + c11 * xa1.z + c12 * xa2.z);
        o1.w = f32_to_bf16(c10 * xa0.w + c11 * xa1.w + c12 * xa2.w);
        o2.x = f32_to_bf16(c20 * xb0.x + c21 * xb1.x + c22 * xb2.x);
        o2.y = f32_to_bf16(c20 * xb0.y + c21 * xb1.y + c22 * xb2.y);
        o2.z = f32_to_bf16(c20 * xb0.z + c21 * xb1.z + c22 * xb2.z);
        o2.w = f32_to_bf16(c20 * xb0.w + c21 * xb1.w + c22 * xb2.w);
        *((ushort4*)(upb + (size_t)v1 * C_IN) + lane16) = o1;
        if (has2) *((ushort4*)(upb + (size_t)v2 * C_IN) + lane16) = o2;
    }
}

// ---------------- Kernel 2: two-pass working-set-split gather gemm ----------
// y[r,n] = relu( sum_f g[r,f]*W[f,n] + bias[n] ), g[r,s*64+c]=up[b,spiral[v,s],c].
// Pass 0 accumulates only slots with spiral < 25000 (3.2 MB working set, fits
// the 4-MB XCD L2); pass 1 the rest. Accumulators for all <=4 of a wave's
// tiles stay in registers across both passes; masked rows load row 0
// (always L2-hot) and get zeroed fragments. W-fragment LDS reads hoisted
// per-kstep over the tile loop so LDS traffic ~= single-pass.
__global__ __launch_bounds__(256, 2) void gemm_kernel(
    const unsigned short* __restrict__ up_bf16,
    const int* __restrict__ spiral,
    const unsigned short* __restrict__ w_frag,
    const float* __restrict__ bias,
    float* __restrict__ out)
{
    __shared__ __align__(16) unsigned short w_lds[WFRAG_ELEMS];  // 36864 B
    int tid = threadIdx.x;
    {   // stage W fragments to LDS once per block
        const uint4* src = (const uint4*)w_frag;
        uint4* dst = (uint4*)w_lds;
#pragma unroll
        for (int i = 0; i < WFRAG_ELEMS / 8 / 256; i++)
            dst[tid + i * 256] = src[tid + i * 256];
    }
    __syncthreads();

    int wave = tid >> 6;
    int lane = tid & 63;
    int m    = lane & 15;
    int quad = lane >> 4;

    int xcd  = blockIdx.x & 7;
    int b    = xcd >> 1;
    int h    = xcd & 1;
    int j    = blockIdx.x >> 3;             // [0, 128)
    int slot = h + 2 * j;                   // [0, 256), block-uniform

    const unsigned short* upb = up_bf16 + (size_t)b * V_OUT * C_IN;
    float* outb = out + (size_t)b * V_OUT * C_OUT;

    int ntile = 0;                          // block-uniform (3 or 4)
#pragma unroll
    for (int it = 0; it < MAXT; it++)
        if (slot + 256 * it < TILES_PER_B) ntile++;

    floatx4 acc[MAXT][2];
#pragma unroll
    for (int it = 0; it < MAXT; it++) {
        acc[it][0] = (floatx4){0.f, 0.f, 0.f, 0.f};
        acc[it][1] = (floatx4){0.f, 0.f, 0.f, 0.f};
    }

    for (int pass = 0; pass < 2; pass++) {
        // reload spiral indices per pass (1.8 MB, L2-resident)
        int sp[MAXT][SPIRAL];
        int valid[MAXT];
#pragma unroll
        for (int it = 0; it < MAXT; it++) {
            if (it >= ntile) continue;
            int vr = (slot + 256 * it) * 64 + wave * 16 + m;
            valid[it] = vr < V_OUT;
            int v = valid[it] ? vr : 0;
#pragma unroll
            for (int s = 0; s < SPIRAL; s++) sp[it][s] = spiral[v * SPIRAL + s];
        }
#pragma unroll
        for (int s = 0; s < SPIRAL; s++) {
            // 4 W-fragments for ksteps 2s, 2s+1 (shared across tiles)
            short8_t wA = *(const short8_t*)(w_lds + (((2 * s + 0) * 2 + 0) * 64 + lane) * 8);
            short8_t wB = *(const short8_t*)(w_lds + (((2 * s + 0) * 2 + 1) * 64 + lane) * 8);
            short8_t wC = *(const short8_t*)(w_lds + (((2 * s + 1) * 2 + 0) * 64 + lane) * 8);
            short8_t wD = *(const short8_t*)(w_lds + (((2 * s + 1) * 2 + 1) * 64 + lane) * 8);
#pragma unroll
            for (int it = 0; it < MAXT; it++) {
                if (it >= ntile) continue;
                int inpass = (sp[it][s] < HALF_V) == (pass == 0);
                int use = valid[it] && inpass;
                int row = use ? sp[it][s] : 0;   // row 0 is always L2-hot
                const unsigned short* rowp = upb + (size_t)row * C_IN;
                short8_t f0 = *(const short8_t*)(rowp + quad * 8);
                short8_t f1 = *(const short8_t*)(rowp + 32 + quad * 8);
                if (!use) {
                    f0 = (short8_t){0, 0, 0, 0, 0, 0, 0, 0};
                    f1 = (short8_t){0, 0, 0, 0, 0, 0, 0, 0};
                }
                acc[it][0] = __builtin_amdgcn_mfma_f32_16x16x32_bf16(wA, f0, acc[it][0], 0, 0, 0);
                acc[it][1] = __builtin_amdgcn_mfma_f32_16x16x32_bf16(wB, f0, acc[it][1], 0, 0, 0);
                acc[it][0] = __builtin_amdgcn_mfma_f32_16x16x32_bf16(wC, f1, acc[it][0], 0, 0, 0);
                acc[it][1] = __builtin_amdgcn_mfma_f32_16x16x32_bf16(wD, f1, acc[it][1], 0, 0, 0);
            }
        }
    }

    // epilogue: lane holds y[r][quad*4..+3] and y[r][16+quad*4..+3] per tile
    float4 bias0 = ((const float4*)bias)[quad];
    float4 bias1 = ((const float4*)bias)[4 + quad];
#pragma unroll
    for (int it = 0; it < MAXT; it++) {
        if (it >= ntile) continue;
        int vr = (slot + 256 * it) * 64 + wave * 16 + m;
        if (vr >= V_OUT) continue;
        float4 o0, o1;
        o0.x = acc[it][0][0] + bias0.x; o0.y = acc[it][0][1] + bias0.y;
        o0.z = acc[it][0][2] + bias0.z; o0.w = acc[it][0][3] + bias0.w;
        o1.x = acc[it][1][0] + bias1.x; o1.y = acc[it][1][1] + bias1.y;
        o1.z = acc[it][1][2] + bias1.z; o1.w = acc[it][1][3] + bias1.w;
        o0.x = o0.x > 0.f ? o0.x : 0.f;  o0.y = o0.y > 0.f ? o0.y : 0.f;
        o0.z = o0.z > 0.f ? o0.z : 0.f;  o0.w = o0.w > 0.f ? o0.w : 0.f;
        o1.x = o1.x > 0.f ? o1.x : 0.f;  o1.y = o1.y > 0.f ? o1.y : 0.f;
        o1.z = o1.z > 0.f ? o1.z : 0.f;  o1.w = o1.w > 0.f ? o1.w : 0.f;
        float* op = outb + (size_t)vr * C_OUT;
        *(float4*)(op + quad * 4)      = o0;
        *(float4*)(op + 16 + quad * 4) = o1;
    }
}

extern "C" void kernel_launch(void* const* d_in, const int* in_sizes, int n_in,
                              void* d_out, int out_size, void* d_ws, size_t ws_size,
                              hipStream_t stream) {
    const float* x      = (const float*)d_in[0];
    const int*   spiral = (const int*)d_in[1];
    const int*   up_idx = (const int*)d_in[2];
    const float* up_val = (const float*)d_in[3];
    const float* weight = (const float*)d_in[4];
    const float* bias   = (const float*)d_in[5];
    float* out = (float*)d_out;

    unsigned short* up_ws  = (unsigned short*)d_ws;          // 200000*64 bf16 = 25.6 MB
    unsigned short* w_frag = up_ws + (size_t)ROWS * C_IN;    // + 36864 B

    upsample_kernel<<<G1 + 1, 256, 0, stream>>>(x, up_idx, up_val, weight, up_ws, w_frag);
    gemm_kernel<<<G2, 256, 0, stream>>>(up_ws, spiral, w_frag, bias, out);
}